// Round 1
// baseline (1032.305 us; speedup 1.0000x reference)
//
#include <hip/hip_runtime.h>

#define TPB 1024
#define CMAX 8
#define LMAX 16
#define HI_MAX 2   // supports H up to 2*TPB with static indexing (H=768 uses 1)

// One block per (batch, mask_type); loops over all L layers internally.
// Exploits exact sparsity of the masked softmax: masked-out positions get
// attention weight exactly 0.0f, so only selected token positions contribute.
// Store-once epilogue: every out element written exactly once -> no memset,
// no global atomics, single dispatch.
__global__ __launch_bounds__(TPB) void mha_agg_fused(
        const float* __restrict__ hidden,
        const int* __restrict__ ids,
        const float* __restrict__ layer_logits,
        const float* __restrict__ scorer_w,
        const int* __restrict__ hte_id_p,
        const int* __restrict__ d_tok,
        const int* __restrict__ window_p,
        float* __restrict__ out,
        int L, int B, int T, int H, int C, int ND)
{
    const int bid  = blockIdx.x;     // b*2 + m
    const int m    = bid & 1;        // 0 = hte window mask, 1 = desc mask
    const int b    = bid >> 1;
    const int tid  = threadIdx.x;
    const int wave = tid >> 6;
    const int lane = tid & 63;
    const int NW   = TPB / 64;

    extern __shared__ unsigned char smem_raw[];
    unsigned short* s_sel    = (unsigned short*)smem_raw;                 // T entries
    float*          s_scores = (float*)(smem_raw + ((2 * T + 15) & ~15)); // T*C floats
    float*          s_sw     = s_scores + (size_t)T * C;                  // C*H floats
    int*            s_misc   = (int*)(s_sw + (size_t)C * H);              // [0]=minpos [1]=count

    if (tid == 0) { s_misc[0] = T; s_misc[1] = 0; }
    // stage scorer weights (C x H, row-major) into LDS
    for (int i = tid; i < C * H; i += TPB) s_sw[i] = scorer_w[i];
    __syncthreads();

    // ---- build selected-position list for this (b, m) — once, reused by all layers ----
    const int* idrow = ids + (size_t)b * T;
    if (m == 0) {
        const int hte = hte_id_p[0];
        for (int t = tid; t < T; t += TPB)
            if (idrow[t] == hte) atomicMin(&s_misc[0], t);
        __syncthreads();
        if (tid == 0) {
            int pos = s_misc[0]; if (pos >= T) pos = T - 1;   // no hte -> T-1
            int win = window_p[0];
            int hi = pos + win; if (hi > T - 1) hi = T - 1;
            int nn = hi - pos + 1;
            for (int i = 0; i < nn; i++) s_sel[i] = (unsigned short)(pos + i);
            s_misc[1] = nn;
        }
    } else {
        int dt[CMAX];
        for (int d = 0; d < ND; d++) dt[d] = d_tok[d];
        for (int t = tid; t < T; t += TPB) {
            int v = idrow[t];
            bool hit = false;
            for (int d = 0; d < ND; d++) hit = hit || (v == dt[d]);
            if (hit) { int idx = atomicAdd(&s_misc[1], 1); s_sel[idx] = (unsigned short)t; }
        }
        __syncthreads();
        if (tid == 0 && s_misc[1] == 0) { s_sel[0] = 0; s_misc[1] = 1; }  // fallback t=0
    }
    __syncthreads();
    const int n = s_misc[1];

    // ---- layer softmax weights (all L, redundant per thread; L=12) ----
    float lw[LMAX];
    float mx = -3.402823466e38f;
    for (int j = 0; j < L; j++) { lw[j] = layer_logits[j]; mx = fmaxf(mx, lw[j]); }
    float den = 0.f;
    for (int j = 0; j < L; j++) { lw[j] = expf(lw[j] - mx); den += lw[j]; }
    const float iden = 1.f / den;

    // ---- per-thread accumulators: thread t owns column h = t (+ hi*TPB), all C channels ----
    float acc0[CMAX];
    float acc1[CMAX];
    for (int c = 0; c < C; c++) { acc0[c] = 0.f; acc1[c] = 0.f; }

    for (int l = 0; l < L; l++) {
        const float* base = hidden + ((size_t)(l + 1) * B + b) * (size_t)T * H;

        // phase 1: scores[i][c] = dot(row_i, scorer_w[c]); one wave per row
        for (int i = wave; i < n; i += NW) {
            const float* row = base + (size_t)s_sel[i] * H;
            float p[CMAX];
            for (int c = 0; c < C; c++) p[c] = 0.f;
            for (int h = lane; h < H; h += 64) {
                float v = row[h];
                for (int c = 0; c < C; c++) p[c] += v * s_sw[c * H + h];
            }
            for (int off = 32; off; off >>= 1)
                for (int c = 0; c < C; c++) p[c] += __shfl_down(p[c], off);
            if (lane == 0)
                for (int c = 0; c < C; c++) s_scores[i * C + c] = p[c];
        }
        __syncthreads();

        // phase 2: per-channel softmax over selected positions, fold in layer weight
        const float lwl = lw[l] * iden;
        for (int c = wave; c < C; c += NW) {
            float smax = -3.402823466e38f;
            for (int i = lane; i < n; i += 64) smax = fmaxf(smax, s_scores[i * C + c]);
            for (int off = 32; off; off >>= 1) smax = fmaxf(smax, __shfl_xor(smax, off));
            float ssum = 0.f;
            for (int i = lane; i < n; i += 64) {
                float e = expf(s_scores[i * C + c] - smax);
                s_scores[i * C + c] = e;
                ssum += e;
            }
            for (int off = 32; off; off >>= 1) ssum += __shfl_xor(ssum, off);
            const float scale = lwl / ssum;
            for (int i = lane; i < n; i += 64) s_scores[i * C + c] *= scale;
        }
        __syncthreads();

        // phase 3: acc[c] += attn[i][c] * row_i[h] for this thread's column(s)
        {
            const int h0 = tid;
            if (h0 < H) {
                for (int i = 0; i < n; i++) {
                    float v = base[(size_t)s_sel[i] * H + h0];
                    for (int c = 0; c < C; c++) acc0[c] += s_scores[i * C + c] * v;
                }
            }
            const int h1 = tid + TPB;
            if (h1 < H) {
                for (int i = 0; i < n; i++) {
                    float v = base[(size_t)s_sel[i] * H + h1];
                    for (int c = 0; c < C; c++) acc1[c] += s_scores[i * C + c] * v;
                }
            }
        }
        __syncthreads();   // s_scores reused by next layer's phase 1
    }

    // ---- epilogue: store-once (poisoned d_out fully overwritten; no memset needed) ----
    float* obase = out + ((size_t)b * 2 + m) * (size_t)C * H;
    if (tid < H)
        for (int c = 0; c < C; c++) obase[c * H + tid] = acc0[c];
    if (tid + TPB < H)
        for (int c = 0; c < C; c++) obase[c * H + tid + TPB] = acc1[c];
}

extern "C" void kernel_launch(void* const* d_in, const int* in_sizes, int n_in,
                              void* d_out, int out_size, void* d_ws, size_t ws_size,
                              hipStream_t stream) {
    const float* hidden = (const float*)d_in[0];   // (L+1, B, T, H) fp32
    const int*   ids    = (const int*)d_in[1];     // (B, T)
    const float* ll     = (const float*)d_in[2];   // (L,)
    const float* sw     = (const float*)d_in[3];   // (C, H)
    const int*   hte    = (const int*)d_in[4];     // scalar
    const int*   dtok   = (const int*)d_in[5];     // (ND,)
    const int*   win    = (const int*)d_in[6];     // scalar
    float*       out    = (float*)d_out;           // (B, 2*C*H)

    const int L  = in_sizes[2];
    const int CH = in_sizes[3];
    const int B  = out_size / (2 * CH);
    const int T  = in_sizes[1] / B;
    const int H  = (int)((long long)in_sizes[0] / ((long long)(L + 1) * in_sizes[1]));
    const int C  = CH / H;
    const int ND = in_sizes[5];

    const size_t smem = (size_t)((2 * T + 15) & ~15)   // sel list (ushort)
                      + (size_t)T * C * sizeof(float)   // scores/attn (worst-case n = T)
                      + (size_t)CH * sizeof(float)      // scorer_w
                      + 16;                             // misc

    // Single dispatch: no memset (store-once epilogue), no global atomics.
    mha_agg_fused<<<B * 2, TPB, smem, stream>>>(hidden, ids, ll, sw, hte, dtok, win, out,
                                                L, B, T, H, C, ND);
}

// Round 2
// 738.028 us; speedup vs baseline: 1.3987x; 1.3987x over previous
//
#include <hip/hip_runtime.h>

#define TPB 256
#define CMAX 8

// One block per (batch, mask_type, layer) — 192 blocks, fully parallel.
// Exploits exact sparsity of the masked softmax: masked-out positions get
// attention weight exactly 0.0f (expf(-1e30 - max) underflows), so only the
// selected token positions (<= window+1 for hte-mask, ~12 for desc-mask)
// contribute. Writes per-layer partials to workspace (store-once, no atomics,
// no memset); a tiny second kernel reduces over L.
__global__ void mha_part_kernel(const float* __restrict__ hidden,
                                const int* __restrict__ ids,
                                const float* __restrict__ layer_logits,
                                const float* __restrict__ scorer_w,
                                const int* __restrict__ hte_id_p,
                                const int* __restrict__ d_tok,
                                const int* __restrict__ window_p,
                                float* __restrict__ dst,   // ws partials, or out (atomic mode)
                                int L, int B, int T, int H, int C, int ND,
                                int atomic_mode)
{
    const int bid  = blockIdx.x;
    const int l    = bid % L;            // layer index (into hidden_states[1:])
    const int m    = (bid / L) & 1;      // 0 = hte window mask, 1 = desc mask
    const int b    = bid / (2 * L);      // batch
    const int tid  = threadIdx.x;
    const int wave = tid >> 6;
    const int lane = tid & 63;

    extern __shared__ unsigned char smem_raw[];
    unsigned short* s_sel    = (unsigned short*)smem_raw;                 // T entries
    float*          s_scores = (float*)(smem_raw + ((2 * T + 15) & ~15)); // T*C floats
    float*          s_sw     = s_scores + (size_t)T * C;                  // C*H floats
    int*            s_misc   = (int*)(s_sw + (size_t)C * H);              // [0]=minpos [1]=count

    if (tid == 0) { s_misc[0] = T; s_misc[1] = 0; }
    // stage scorer weights (C x H, row-major) into LDS
    for (int i = tid; i < C * H; i += TPB) s_sw[i] = scorer_w[i];
    __syncthreads();

    // ---- build selected-position list for this (b, m) ----
    const int* idrow = ids + (size_t)b * T;
    if (m == 0) {
        const int hte = hte_id_p[0];
        for (int t = tid; t < T; t += TPB)
            if (idrow[t] == hte) atomicMin(&s_misc[0], t);
        __syncthreads();
        if (tid == 0) {
            int pos = s_misc[0]; if (pos >= T) pos = T - 1;   // no hte -> T-1
            int win = window_p[0];
            int hi = pos + win; if (hi > T - 1) hi = T - 1;
            int nn = hi - pos + 1;
            for (int i = 0; i < nn; i++) s_sel[i] = (unsigned short)(pos + i);
            s_misc[1] = nn;
        }
    } else {
        int dt[CMAX];
        for (int d = 0; d < ND; d++) dt[d] = d_tok[d];
        for (int t = tid; t < T; t += TPB) {
            int v = idrow[t];
            bool hit = false;
            for (int d = 0; d < ND; d++) hit = hit || (v == dt[d]);
            if (hit) { int idx = atomicAdd(&s_misc[1], 1); s_sel[idx] = (unsigned short)t; }
        }
        __syncthreads();
        if (tid == 0 && s_misc[1] == 0) { s_sel[0] = 0; s_misc[1] = 1; }  // fallback t=0
    }
    __syncthreads();
    const int n = s_misc[1];

    // ---- layer weight: softmax over layer_logits, pick element l (redundant per thread, L=12) ----
    float mx = -3.402823466e38f;
    for (int j = 0; j < L; j++) mx = fmaxf(mx, layer_logits[j]);
    float den = 0.f;
    for (int j = 0; j < L; j++) den += expf(layer_logits[j] - mx);
    const float lwl = expf(layer_logits[l] - mx) / den;

    const float* base = hidden + ((size_t)(l + 1) * B + b) * (size_t)T * H;
    const bool vec4 = ((H & 3) == 0) && (((T * C) & 3) == 0);  // 16B alignment of rows & s_sw

    // ---- phase 1: scores[i][c] = dot(row_i, scorer_w[c]); one wave per row ----
    for (int i = wave; i < n; i += TPB / 64) {
        const float* row = base + (size_t)s_sel[i] * H;
        float p[CMAX];
        for (int c = 0; c < C; c++) p[c] = 0.f;
        if (vec4) {
            const float4* row4 = (const float4*)row;
            const int H4 = H >> 2;
            for (int h4 = lane; h4 < H4; h4 += 64) {
                const float4 v = row4[h4];
                for (int c = 0; c < C; c++) {
                    const float4 w = *(const float4*)(s_sw + (size_t)c * H + (h4 << 2));
                    p[c] += v.x * w.x + v.y * w.y + v.z * w.z + v.w * w.w;
                }
            }
        } else {
            for (int h = lane; h < H; h += 64) {
                float v = row[h];
                for (int c = 0; c < C; c++) p[c] += v * s_sw[c * H + h];
            }
        }
        for (int off = 32; off; off >>= 1)
            for (int c = 0; c < C; c++) p[c] += __shfl_down(p[c], off);
        if (lane == 0)
            for (int c = 0; c < C; c++) s_scores[i * C + c] = p[c];
    }
    __syncthreads();

    // ---- phase 2: per-channel softmax over selected positions, fold in lwl ----
    for (int c = wave; c < C; c += TPB / 64) {
        float smax = -3.402823466e38f;
        for (int i = lane; i < n; i += 64) smax = fmaxf(smax, s_scores[i * C + c]);
        for (int off = 32; off; off >>= 1) smax = fmaxf(smax, __shfl_xor(smax, off));
        float ssum = 0.f;
        for (int i = lane; i < n; i += 64) {
            float e = expf(s_scores[i * C + c] - smax);
            s_scores[i * C + c] = e;
            ssum += e;
        }
        for (int off = 32; off; off >>= 1) ssum += __shfl_xor(ssum, off);
        const float scale = lwl / ssum;
        for (int i = lane; i < n; i += 64) s_scores[i * C + c] *= scale;
    }
    __syncthreads();

    // ---- phase 3: partial[c][h] = sum_i attn[i][c] * row_i[h] (rows L2-hot from phase 1) ----
    if (atomic_mode) {
        float* obase = dst + ((size_t)b * 2 + m) * (size_t)C * H;
        for (int h = tid; h < H; h += TPB) {
            float a[CMAX];
            for (int c = 0; c < C; c++) a[c] = 0.f;
            for (int i = 0; i < n; i++) {
                float v = base[(size_t)s_sel[i] * H + h];
                for (int c = 0; c < C; c++) a[c] += s_scores[i * C + c] * v;
            }
            for (int c = 0; c < C; c++) atomicAdd(obase + c * H + h, a[c]);
        }
    } else {
        float* pbase = dst + (size_t)bid * C * H;   // bid == (b*2+m)*L + l
        if (vec4) {
            const int H4 = H >> 2;
            for (int h4 = tid; h4 < H4; h4 += TPB) {
                float4 a[CMAX];
                for (int c = 0; c < C; c++) a[c] = make_float4(0.f, 0.f, 0.f, 0.f);
                for (int i = 0; i < n; i++) {
                    const float4 v = *(const float4*)(base + (size_t)s_sel[i] * H + (h4 << 2));
                    for (int c = 0; c < C; c++) {
                        const float s = s_scores[i * C + c];
                        a[c].x += s * v.x; a[c].y += s * v.y;
                        a[c].z += s * v.z; a[c].w += s * v.w;
                    }
                }
                for (int c = 0; c < C; c++)
                    *(float4*)(pbase + (size_t)c * H + (h4 << 2)) = a[c];
            }
        } else {
            for (int h = tid; h < H; h += TPB) {
                float a[CMAX];
                for (int c = 0; c < C; c++) a[c] = 0.f;
                for (int i = 0; i < n; i++) {
                    float v = base[(size_t)s_sel[i] * H + h];
                    for (int c = 0; c < C; c++) a[c] += s_scores[i * C + c] * v;
                }
                for (int c = 0; c < C; c++) pbase[c * H + h] = a[c];
            }
        }
    }
}

// out[bm*CH + ch] = sum_l part[(bm*L + l)*CH + ch]; store-once over poisoned d_out.
__global__ void mha_reduce_kernel(const float* __restrict__ part,
                                  float* __restrict__ out,
                                  int L, int CH, int total)
{
    const int i = blockIdx.x * blockDim.x + threadIdx.x;
    if (i >= total) return;
    const int bm = i / CH;
    const int ch = i - bm * CH;
    const float* p = part + (size_t)bm * L * CH + ch;
    float s = 0.f;
#pragma unroll 4
    for (int l = 0; l < L; l++) s += p[(size_t)l * CH];
    out[i] = s;
}

extern "C" void kernel_launch(void* const* d_in, const int* in_sizes, int n_in,
                              void* d_out, int out_size, void* d_ws, size_t ws_size,
                              hipStream_t stream) {
    const float* hidden = (const float*)d_in[0];   // (L+1, B, T, H) fp32
    const int*   ids    = (const int*)d_in[1];     // (B, T)
    const float* ll     = (const float*)d_in[2];   // (L,)
    const float* sw     = (const float*)d_in[3];   // (C, H)
    const int*   hte    = (const int*)d_in[4];     // scalar
    const int*   dtok   = (const int*)d_in[5];     // (ND,)
    const int*   win    = (const int*)d_in[6];     // scalar
    float*       out    = (float*)d_out;           // (B, 2*C*H)

    const int L  = in_sizes[2];
    const int CH = in_sizes[3];
    const int B  = out_size / (2 * CH);
    const int T  = in_sizes[1] / B;
    const int H  = (int)((long long)in_sizes[0] / ((long long)(L + 1) * in_sizes[1]));
    const int C  = CH / H;
    const int ND = in_sizes[5];

    const size_t smem = (size_t)((2 * T + 15) & ~15)   // sel list (ushort)
                      + (size_t)T * C * sizeof(float)   // scores/attn
                      + (size_t)CH * sizeof(float)      // scorer_w
                      + 16;                             // misc

    const size_t part_bytes = (size_t)B * 2 * L * CH * sizeof(float);

    if (d_ws != nullptr && ws_size >= part_bytes) {
        // Store-once partials path: no memset, no global atomics.
        mha_part_kernel<<<B * 2 * L, TPB, smem, stream>>>(
            hidden, ids, ll, sw, hte, dtok, win, (float*)d_ws,
            L, B, T, H, C, ND, 0);
        const int total = B * 2 * CH;
        mha_reduce_kernel<<<(total + 255) / 256, 256, 0, stream>>>(
            (float*)d_ws, out, L, CH, total);
    } else {
        // Fallback: proven memset + atomic accumulation path.
        hipMemsetAsync(d_out, 0, (size_t)out_size * sizeof(float), stream);
        mha_part_kernel<<<B * 2 * L, TPB, smem, stream>>>(
            hidden, ids, ll, sw, hte, dtok, win, out,
            L, B, T, H, C, ND, 1);
    }
}